// Round 7
// baseline (246.622 us; speedup 1.0000x reference)
//
#include <hip/hip_runtime.h>
#include <hip/hip_bf16.h>

#define NB 32
#define CD 256
#define SS 1024
#define DD 256
#define TT 512
// SCALE * log2(e): softmax computed in base-2
#define QSCALE 0.09016844f

typedef __attribute__((ext_vector_type(8))) short s16x8;
typedef __attribute__((ext_vector_type(4))) short s16x4;
typedef __attribute__((ext_vector_type(4))) float f32x4;
typedef __attribute__((ext_vector_type(16))) float f32x16;

__device__ __forceinline__ unsigned short f2bf(float f) {
  unsigned u = __builtin_bit_cast(unsigned, f);
  u = (u + 0x7FFFu + ((u >> 16) & 1u)) >> 16;
  return (unsigned short)u;
}
__device__ __forceinline__ float bf2f(unsigned short h) {
  return __builtin_bit_cast(float, ((unsigned)h) << 16);
}
__device__ __forceinline__ unsigned pk2(float a, float b) {
  float2 f2; f2.x = a; f2.y = b;
  __hip_bfloat162 h = __float22bfloat162_rn(f2);
  unsigned u;
  __builtin_memcpy(&u, &h, 4);
  return u;
}
#define GLOAD16(gp, lp)                                                        \
  __builtin_amdgcn_global_load_lds(                                            \
      (const __attribute__((address_space(1))) unsigned int*)(const void*)(gp),\
      (__attribute__((address_space(3))) unsigned int*)(void*)(lp), 16, 0, 0)

// ---- misc: blocks 0..1023 = weight fp32->bf16; 1024..1055 = temb ----
__global__ __launch_bounds__(256) void k_misc(const float* __restrict__ t,
    const float* __restrict__ Wt, const float* __restrict__ bt, float* __restrict__ temb,
    const float* __restrict__ wq, const float* __restrict__ wk,
    const float* __restrict__ wv, const float* __restrict__ wp,
    unsigned short* __restrict__ dst) {
  const int b = blockIdx.x;
  if (b < 1024) {
    const int i = b * 256 + threadIdx.x;
    const int which = i >> 16, off = i & 65535;
    const float* s = which == 0 ? wq : which == 1 ? wk : which == 2 ? wv : wp;
    dst[i] = f2bf(s[off]);
  } else {
    const int n = b - 1024, c = threadIdx.x;
    const float4* tv = (const float4*)(t + (size_t)n * TT);
    const float4* wvv = (const float4*)(Wt + (size_t)c * TT);
    float acc = 0.f;
#pragma unroll 8
    for (int i = 0; i < TT / 4; ++i) {
      float4 a = tv[i], bb = wvv[i];
      acc += a.x * bb.x + a.y * bb.y + a.z * bb.z + a.w * bb.w;
    }
    acc += bt[c];
    temb[n * CD + c] = fmaxf(acc, 0.f);
  }
}

// ---- xb[n, s, c] = bf16(x[n,c,s] + temb[n,c]) ----
__global__ __launch_bounds__(256) void k_addT(const float* __restrict__ x,
    const float* __restrict__ temb, unsigned short* __restrict__ xb) {
  __shared__ float tile[32][33];
  const int tx = threadIdx.x & 31, ty = threadIdx.x >> 5;
  const int n = blockIdx.z, s0 = blockIdx.y * 32, c0 = blockIdx.x * 32;
#pragma unroll
  for (int i = 0; i < 4; ++i) {
    const int cc = ty + i * 8;
    tile[cc][tx] = x[((size_t)n * CD + c0 + cc) * SS + s0 + tx] + temb[n * CD + c0 + cc];
  }
  __syncthreads();
  unsigned short* op = xb + ((size_t)n * SS + s0) * CD + c0;
#pragma unroll
  for (int i = 0; i < 4; ++i) {
    const int ss = ty + i * 8;
    op[(size_t)ss * CD + tx] = f2bf(tile[tx][ss]);
  }
}

// ---- QKV GEMM: z = which*32 + n. which==2 writes V transposed. ----
__global__ __launch_bounds__(256) void k_qkv(const unsigned short* __restrict__ A,
    const unsigned short* __restrict__ wb, unsigned short* __restrict__ qb,
    unsigned short* __restrict__ kb, unsigned short* __restrict__ vtb) {
  __shared__ __attribute__((aligned(16))) unsigned short As[128 * 32];
  __shared__ __attribute__((aligned(16))) unsigned short Bs[128 * 32];
  const int which = blockIdx.z >> 5, n = blockIdx.z & 31;
  const int s0 = blockIdx.x * 128;
  const int d0 = blockIdx.y * 128;
  const unsigned short* B = wb + which * 65536;
  const int tid = threadIdx.x;
  const int lane = tid & 63, wid = tid >> 6;
  const int lo = lane & 15, hi = lane >> 4;
  const int wr = wid >> 1, wc = wid & 1;
  const unsigned short* An = A + (size_t)n * SS * CD;
  f32x4 acc[4][4] = {};
  for (int k0 = 0; k0 < CD; k0 += 32) {
#pragma unroll
    for (int i = 0; i < 2; ++i) {
      const int seg = i * 256 + wid * 64 + lane;
      const int row = seg >> 2, c8 = seg & 3;
      GLOAD16(An + (size_t)(s0 + row) * CD + k0 + c8 * 8, As + (size_t)(i * 256 + wid * 64) * 8);
      GLOAD16(B + (size_t)(d0 + row) * CD + k0 + c8 * 8, Bs + (size_t)(i * 256 + wid * 64) * 8);
    }
    __syncthreads();
    s16x8 a[4], b[4];
#pragma unroll
    for (int mi = 0; mi < 4; ++mi)
      a[mi] = *(const s16x8*)&As[(wr * 64 + mi * 16 + lo) * 32 + hi * 8];
#pragma unroll
    for (int ni = 0; ni < 4; ++ni)
      b[ni] = *(const s16x8*)&Bs[(wc * 64 + ni * 16 + lo) * 32 + hi * 8];
#pragma unroll
    for (int mi = 0; mi < 4; ++mi)
#pragma unroll
      for (int ni = 0; ni < 4; ++ni)
        acc[mi][ni] = __builtin_amdgcn_mfma_f32_16x16x32_bf16(a[mi], b[ni], acc[mi][ni], 0, 0, 0);
    __syncthreads();
  }
  if (which < 2) {
    const float osc = which == 0 ? QSCALE : 1.0f;
    unsigned short* On = (which == 0 ? qb : kb) + (size_t)n * SS * DD;
#pragma unroll
    for (int mi = 0; mi < 4; ++mi) {
      const int r0 = s0 + wr * 64 + mi * 16 + hi * 4;
#pragma unroll
      for (int ni = 0; ni < 4; ++ni) {
        const int col = d0 + wc * 64 + ni * 16 + lo;
#pragma unroll
        for (int r = 0; r < 4; ++r)
          On[(size_t)(r0 + r) * DD + col] = f2bf(acc[mi][ni][r] * osc);
      }
    }
  } else {
    unsigned short* On = vtb + (size_t)n * DD * SS;
#pragma unroll
    for (int mi = 0; mi < 4; ++mi) {
      const int r0 = s0 + wr * 64 + mi * 16 + hi * 4;
#pragma unroll
      for (int ni = 0; ni < 4; ++ni) {
        const int col = d0 + wc * 64 + ni * 16 + lo;
        s16x4 v;
#pragma unroll
        for (int r = 0; r < 4; ++r) v[r] = (short)f2bf(acc[mi][ni][r]);
        *(s16x4*)&On[(size_t)col * SS + r0] = v;
      }
    }
  }
}

// ---- flash attention with kv-split. grid 1024: qt=bid&7, dh=(bid>>3)&1,
// kv=(bid>>4)&1, n=bid>>5. 4 waves x 32 q-rows; lane owns q=lane&31.
// K single-buffered (16KB), V^T double-buffered (2x8KB), P per-wave (10KB)
// => 42KB LDS => 3 blocks/CU. Softmax in base-2 (scale folded into Q).
// Writes normalized partial O + (m,l) per kv half. ----
__global__ __launch_bounds__(256, 3) void k_attn(const unsigned short* __restrict__ qb,
    const unsigned short* __restrict__ kb, const unsigned short* __restrict__ vtb,
    unsigned short* __restrict__ op1, unsigned short* __restrict__ op2,
    float2* __restrict__ ml) {
  // ushort elems: Ks[8192] @0, Vs[2][4096] @8192, P[4][32*40] @16384
  __shared__ __attribute__((aligned(16))) unsigned short lds[21504];  // 42KB
  const int bid = blockIdx.x;
  const int qt = bid & 7, dh = (bid >> 3) & 1, kv = (bid >> 4) & 1, n = bid >> 5;
  const int tid = threadIdx.x, lane = tid & 63, w = tid >> 6;
  const int l31 = lane & 31, h = lane >> 5;
  const int dblk = dh * 128;
  const unsigned short* Kn = kb + (size_t)n * SS * DD;
  const unsigned short* Vn = vtb + ((size_t)n * DD + dblk) * SS;
  unsigned short* Pw = lds + 16384 + w * 1280;  // [32][40]
  const int qrow = qt * 128 + w * 32 + l31;

  const unsigned short* Qp = qb + ((size_t)n * SS + qrow) * DD + h * 8;
  s16x8 qf[16];
#pragma unroll
  for (int ks = 0; ks < 16; ++ks) qf[ks] = *(const s16x8*)(Qp + ks * 16);

  f32x16 acc[4] = {};
  float mrun = -3.0e38f, lrun = 0.f;

  auto STAGE_K = [&](int jt) {
    const int j0 = jt * 32;
#pragma unroll
    for (int i = 0; i < 4; ++i) {
      const int idx = i * 256 + w * 64 + lane;
      const int row = idx >> 5, c8 = idx & 31;
      GLOAD16(Kn + (size_t)(j0 + row) * DD + ((c8 ^ (row & 7)) << 3),
              lds + (size_t)(i * 256 + w * 64) * 8);
    }
  };
  auto STAGE_V = [&](int buf, int jt) {
    const int j0 = jt * 32;
    unsigned short* VsB = lds + 8192 + buf * 4096;
#pragma unroll
    for (int i = 0; i < 2; ++i) {
      const int idx = i * 256 + w * 64 + lane;
      const int row = idx >> 2, c8 = idx & 3;
      GLOAD16(Vn + (size_t)row * SS + j0 + ((c8 ^ ((row >> 1) & 3)) << 3),
              VsB + (size_t)(i * 256 + w * 64) * 8);
    }
  };

  const int t0 = kv * 16, t1 = t0 + 16;
  STAGE_K(t0);
  STAGE_V(0, t0);
  __syncthreads();

  int cur = 0;
#pragma unroll 1
  for (int jt = t0; jt < t1; ++jt) {
    // ---- QK^T from single K buffer: lane holds S[j=crow(r,h)][q=l31] ----
    f32x16 sc = {};
    __builtin_amdgcn_s_setprio(1);
#pragma unroll
    for (int ks = 0; ks < 16; ++ks) {
      const s16x8 kf = *(const s16x8*)&lds[l31 * 256 + ((((ks * 2 + h)) ^ (l31 & 7)) << 3)];
      sc = __builtin_amdgcn_mfma_f32_32x32x16_bf16(kf, qf[ks], sc, 0, 0, 0);
    }
    __builtin_amdgcn_s_setprio(0);
    __syncthreads();  // all waves done reading Ks; no vmem outstanding
    if (jt + 1 < t1) {
      STAGE_K(jt + 1);
      STAGE_V(cur ^ 1, jt + 1);
    }
    // ---- online softmax in base-2; row = pair {lane, lane^32} ----
    float pm = sc[0];
#pragma unroll
    for (int i = 1; i < 16; ++i) pm = fmaxf(pm, sc[i]);
    pm = fmaxf(pm, __shfl_xor(pm, 32, 64));
    if (__any(pm > mrun + 8.f)) {
      const float mn = fmaxf(mrun, pm);
      const float corr = exp2f(mrun - mn);
      mrun = mn; lrun *= corr;
#pragma unroll
      for (int dc = 0; dc < 4; ++dc)
#pragma unroll
        for (int i = 0; i < 16; ++i) acc[dc][i] *= corr;
    }
#pragma unroll
    for (int i = 0; i < 16; ++i) sc[i] = exp2f(sc[i] - mrun);
    lrun += (((sc[0] + sc[1]) + (sc[2] + sc[3])) + ((sc[4] + sc[5]) + (sc[6] + sc[7]))) +
            (((sc[8] + sc[9]) + (sc[10] + sc[11])) + ((sc[12] + sc[13]) + (sc[14] + sc[15])));
    // ---- P -> per-wave LDS at [q][crow] (same-wave write->read) ----
#pragma unroll
    for (int t = 0; t < 4; ++t) {
      uint2 u;
      u.x = pk2(sc[t * 4 + 0], sc[t * 4 + 1]);
      u.y = pk2(sc[t * 4 + 2], sc[t * 4 + 3]);
      *(uint2*)&Pw[l31 * 40 + t * 8 + h * 4] = u;
    }
    const s16x8 pa0 = *(const s16x8*)&Pw[l31 * 40 + h * 8];
    const s16x8 pa1 = *(const s16x8*)&Pw[l31 * 40 + 16 + h * 8];
    // ---- PV from Vs[cur] ----
    const unsigned short* Vs = lds + 8192 + cur * 4096;
    __builtin_amdgcn_s_setprio(1);
#pragma unroll
    for (int dc = 0; dc < 4; ++dc) {
      const s16x8 vf0 = *(const s16x8*)&Vs[(dc * 32 + l31) * 32 + ((h ^ ((l31 >> 1) & 3)) << 3)];
      acc[dc] = __builtin_amdgcn_mfma_f32_32x32x16_bf16(vf0, pa0, acc[dc], 0, 0, 0);
    }
#pragma unroll
    for (int dc = 0; dc < 4; ++dc) {
      const s16x8 vf1 = *(const s16x8*)&Vs[(dc * 32 + l31) * 32 + (((2 + h) ^ ((l31 >> 1) & 3)) << 3)];
      acc[dc] = __builtin_amdgcn_mfma_f32_32x32x16_bf16(vf1, pa1, acc[dc], 0, 0, 0);
    }
    __builtin_amdgcn_s_setprio(0);
    __syncthreads();  // drains vmcnt(0): next K/V staged; waves past Vs[cur]
    cur ^= 1;
  }
  lrun += __shfl_xor(lrun, 32, 64);
  const float inv = 1.0f / lrun;
  unsigned short* Op = (kv == 0 ? op1 : op2) + ((size_t)n * SS + qrow) * DD + dblk;
#pragma unroll
  for (int dc = 0; dc < 4; ++dc)
#pragma unroll
    for (int rg = 0; rg < 4; ++rg) {
      uint2 u;
      u.x = pk2(acc[dc][rg * 4 + 0] * inv, acc[dc][rg * 4 + 1] * inv);
      u.y = pk2(acc[dc][rg * 4 + 2] * inv, acc[dc][rg * 4 + 3] * inv);
      *(uint2*)(Op + dc * 32 + rg * 8 + h * 4) = u;
    }
  if (h == 0) {
    float2 v; v.x = mrun; v.y = lrun;
    ml[(size_t)kv * (NB * SS) + n * SS + qrow] = v;
  }
}

// ---- combine kv-split partials: ob = a1*op1 + a2*op2 (in-place ob==op2 ok) ----
__global__ __launch_bounds__(256) void k_comb(const unsigned short* __restrict__ op1,
    const unsigned short* __restrict__ op2, const float2* __restrict__ ml,
    unsigned short* __restrict__ ob) {
  const int b = blockIdx.x;                 // 32 n x 128 q-chunks
  const int n = b >> 7, q = (b & 127) * 8 + (threadIdx.x >> 5);
  const int d8 = (threadIdx.x & 31) * 8;
  const float2 a = ml[(size_t)n * SS + q];
  const float2 c = ml[(size_t)NB * SS + (size_t)n * SS + q];
  const float M = fmaxf(a.x, c.x);
  const float w1 = exp2f(a.x - M) * a.y;
  const float w2 = exp2f(c.x - M) * c.y;
  const float inv = 1.0f / (w1 + w2);
  const float a1 = w1 * inv, a2 = w2 * inv;
  const size_t off = ((size_t)n * SS + q) * DD + d8;
  const s16x8 o1 = *(const s16x8*)(op1 + off);
  const s16x8 o2 = *(const s16x8*)(op2 + off);
  float v[8];
#pragma unroll
  for (int i = 0; i < 8; ++i)
    v[i] = a1 * bf2f((unsigned short)o1[i]) + a2 * bf2f((unsigned short)o2[i]);
  uint4 u;
  u.x = pk2(v[0], v[1]); u.y = pk2(v[2], v[3]);
  u.z = pk2(v[4], v[5]); u.w = pk2(v[6], v[7]);
  *(uint4*)(ob + off) = u;
}

// ---- fused proj + bias + residual ----
__global__ __launch_bounds__(256) void k_proj(const unsigned short* __restrict__ ob,
    const unsigned short* __restrict__ wpb, const float* __restrict__ bp,
    const float* __restrict__ x, float* __restrict__ out) {
  __shared__ __attribute__((aligned(16))) unsigned short As[128 * 32];
  __shared__ __attribute__((aligned(16))) unsigned short Bs[128 * 32];
  const int n = blockIdx.z;
  const int s0 = blockIdx.x * 128;
  const int c0 = blockIdx.y * 128;
  const int tid = threadIdx.x;
  const int lane = tid & 63, wid = tid >> 6;
  const int lo = lane & 15, hi = lane >> 4;
  const int wr = wid >> 1, wc = wid & 1;
  const unsigned short* On = ob + (size_t)n * SS * DD;
  f32x4 acc[4][4] = {};
  for (int k0 = 0; k0 < DD; k0 += 32) {
#pragma unroll
    for (int i = 0; i < 2; ++i) {
      const int seg = i * 256 + wid * 64 + lane;
      const int row = seg >> 2, c8 = seg & 3;
      GLOAD16(wpb + (size_t)(c0 + row) * DD + k0 + c8 * 8, As + (size_t)(i * 256 + wid * 64) * 8);
      GLOAD16(On + (size_t)(s0 + row) * DD + k0 + c8 * 8, Bs + (size_t)(i * 256 + wid * 64) * 8);
    }
    __syncthreads();
    s16x8 a[4], b[4];
#pragma unroll
    for (int mi = 0; mi < 4; ++mi)
      a[mi] = *(const s16x8*)&As[(wr * 64 + mi * 16 + lo) * 32 + hi * 8];
#pragma unroll
    for (int ni = 0; ni < 4; ++ni)
      b[ni] = *(const s16x8*)&Bs[(wc * 64 + ni * 16 + lo) * 32 + hi * 8];
#pragma unroll
    for (int mi = 0; mi < 4; ++mi)
#pragma unroll
      for (int ni = 0; ni < 4; ++ni)
        acc[mi][ni] = __builtin_amdgcn_mfma_f32_16x16x32_bf16(a[mi], b[ni], acc[mi][ni], 0, 0, 0);
    __syncthreads();
  }
#pragma unroll
  for (int mi = 0; mi < 4; ++mi) {
#pragma unroll
    for (int r = 0; r < 4; ++r) {
      const int c = c0 + wr * 64 + mi * 16 + hi * 4 + r;
      const float bpc = bp[c];
      const size_t base = ((size_t)n * CD + c) * SS;
#pragma unroll
      for (int ni = 0; ni < 4; ++ni) {
        const int s = s0 + wc * 64 + ni * 16 + lo;
        out[base + s] = acc[mi][ni][r] + bpc + x[base + s];
      }
    }
  }
}

extern "C" void kernel_launch(void* const* d_in, const int* in_sizes, int n_in,
                              void* d_out, int out_size, void* d_ws, size_t ws_size,
                              hipStream_t stream) {
  const float* x  = (const float*)d_in[0];
  const float* t  = (const float*)d_in[1];
  const float* Wt = (const float*)d_in[2];
  const float* bt = (const float*)d_in[3];
  const float* Wq = (const float*)d_in[4];
  const float* Wk = (const float*)d_in[5];
  const float* Wv = (const float*)d_in[6];
  const float* Wp = (const float*)d_in[7];
  const float* bp = (const float*)d_in[8];
  char* ws = (char*)d_ws;
  float* temb        = (float*)ws;                              // 32 KB
  unsigned short* wb = (unsigned short*)(ws + 32768);           // 512 KB (q,k,v,p)
  unsigned short* xb = (unsigned short*)(ws + 557056);          // 16 MB [n,s,c]; reused as op1
  unsigned short* qb = (unsigned short*)(ws + 17334272);        // 16 MB [n,s,d]
  unsigned short* kb = (unsigned short*)(ws + 34111488);        // 16 MB [n,s,d]
  unsigned short* vtb = (unsigned short*)(ws + 50888704);       // 16 MB [n,d,s]
  unsigned short* ob = (unsigned short*)(ws + 67665920);        // 16 MB [n,s,d]; also op2
  float2* ml         = (float2*)(ws + 84443136);                // 512 KB
  unsigned short* op1 = xb;
  unsigned short* op2 = ob;
  float* out = (float*)d_out;

  k_misc<<<1056, 256, 0, stream>>>(t, Wt, bt, temb, Wq, Wk, Wv, Wp, wb);
  k_addT<<<dim3(8, 32, 32), 256, 0, stream>>>(x, temb, xb);
  k_qkv<<<dim3(8, 2, 96), 256, 0, stream>>>(xb, wb, qb, kb, vtb);
  k_attn<<<1024, 256, 0, stream>>>(qb, kb, vtb, op1, op2, ml);
  k_comb<<<4096, 256, 0, stream>>>(op1, op2, ml, ob);
  k_proj<<<dim3(8, 2, 32), 256, 0, stream>>>(ob, wb + 196608, bp, x, out);
}

// Round 8
// 145.478 us; speedup vs baseline: 1.6952x; 1.6952x over previous
//
#include <hip/hip_runtime.h>
#include <hip/hip_bf16.h>

#define NB 32
#define CD 256
#define SS 1024
#define DD 256
#define TT 512
// SCALE * log2(e): softmax computed in base-2
#define QSCALE 0.09016844f

typedef __attribute__((ext_vector_type(8))) short s16x8;
typedef __attribute__((ext_vector_type(4))) short s16x4;
typedef __attribute__((ext_vector_type(4))) float f32x4;
typedef __attribute__((ext_vector_type(16))) float f32x16;

__device__ __forceinline__ unsigned short f2bf(float f) {
  unsigned u = __builtin_bit_cast(unsigned, f);
  u = (u + 0x7FFFu + ((u >> 16) & 1u)) >> 16;
  return (unsigned short)u;
}
__device__ __forceinline__ float bf2f(unsigned short h) {
  return __builtin_bit_cast(float, ((unsigned)h) << 16);
}
__device__ __forceinline__ unsigned pk2(float a, float b) {
  float2 f2; f2.x = a; f2.y = b;
  __hip_bfloat162 h = __float22bfloat162_rn(f2);
  unsigned u;
  __builtin_memcpy(&u, &h, 4);
  return u;
}
#define GLOAD16(gp, lp)                                                        \
  __builtin_amdgcn_global_load_lds(                                            \
      (const __attribute__((address_space(1))) unsigned int*)(const void*)(gp),\
      (__attribute__((address_space(3))) unsigned int*)(void*)(lp), 16, 0, 0)

// ---- misc: blocks 0..1023 = weight fp32->bf16; 1024..1055 = temb ----
__global__ __launch_bounds__(256) void k_misc(const float* __restrict__ t,
    const float* __restrict__ Wt, const float* __restrict__ bt, float* __restrict__ temb,
    const float* __restrict__ wq, const float* __restrict__ wk,
    const float* __restrict__ wv, const float* __restrict__ wp,
    unsigned short* __restrict__ dst) {
  const int b = blockIdx.x;
  if (b < 1024) {
    const int i = b * 256 + threadIdx.x;
    const int which = i >> 16, off = i & 65535;
    const float* s = which == 0 ? wq : which == 1 ? wk : which == 2 ? wv : wp;
    dst[i] = f2bf(s[off]);
  } else {
    const int n = b - 1024, c = threadIdx.x;
    const float4* tv = (const float4*)(t + (size_t)n * TT);
    const float4* wvv = (const float4*)(Wt + (size_t)c * TT);
    float acc = 0.f;
#pragma unroll 8
    for (int i = 0; i < TT / 4; ++i) {
      float4 a = tv[i], bb = wvv[i];
      acc += a.x * bb.x + a.y * bb.y + a.z * bb.z + a.w * bb.w;
    }
    acc += bt[c];
    temb[n * CD + c] = fmaxf(acc, 0.f);
  }
}

// ---- xb[n, s, c] = bf16(x[n,c,s] + temb[n,c]) ----
__global__ __launch_bounds__(256) void k_addT(const float* __restrict__ x,
    const float* __restrict__ temb, unsigned short* __restrict__ xb) {
  __shared__ float tile[32][33];
  const int tx = threadIdx.x & 31, ty = threadIdx.x >> 5;
  const int n = blockIdx.z, s0 = blockIdx.y * 32, c0 = blockIdx.x * 32;
#pragma unroll
  for (int i = 0; i < 4; ++i) {
    const int cc = ty + i * 8;
    tile[cc][tx] = x[((size_t)n * CD + c0 + cc) * SS + s0 + tx] + temb[n * CD + c0 + cc];
  }
  __syncthreads();
  unsigned short* op = xb + ((size_t)n * SS + s0) * CD + c0;
#pragma unroll
  for (int i = 0; i < 4; ++i) {
    const int ss = ty + i * 8;
    op[(size_t)ss * CD + tx] = f2bf(tile[tx][ss]);
  }
}

// ---- QKV GEMM: z = which*32 + n. which==2 writes V transposed. ----
__global__ __launch_bounds__(256) void k_qkv(const unsigned short* __restrict__ A,
    const unsigned short* __restrict__ wb, unsigned short* __restrict__ qb,
    unsigned short* __restrict__ kb, unsigned short* __restrict__ vtb) {
  __shared__ __attribute__((aligned(16))) unsigned short As[128 * 32];
  __shared__ __attribute__((aligned(16))) unsigned short Bs[128 * 32];
  const int which = blockIdx.z >> 5, n = blockIdx.z & 31;
  const int s0 = blockIdx.x * 128;
  const int d0 = blockIdx.y * 128;
  const unsigned short* B = wb + which * 65536;
  const int tid = threadIdx.x;
  const int lane = tid & 63, wid = tid >> 6;
  const int lo = lane & 15, hi = lane >> 4;
  const int wr = wid >> 1, wc = wid & 1;
  const unsigned short* An = A + (size_t)n * SS * CD;
  f32x4 acc[4][4] = {};
  for (int k0 = 0; k0 < CD; k0 += 32) {
#pragma unroll
    for (int i = 0; i < 2; ++i) {
      const int seg = i * 256 + wid * 64 + lane;
      const int row = seg >> 2, c8 = seg & 3;
      GLOAD16(An + (size_t)(s0 + row) * CD + k0 + c8 * 8, As + (size_t)(i * 256 + wid * 64) * 8);
      GLOAD16(B + (size_t)(d0 + row) * CD + k0 + c8 * 8, Bs + (size_t)(i * 256 + wid * 64) * 8);
    }
    __syncthreads();
    s16x8 a[4], b[4];
#pragma unroll
    for (int mi = 0; mi < 4; ++mi)
      a[mi] = *(const s16x8*)&As[(wr * 64 + mi * 16 + lo) * 32 + hi * 8];
#pragma unroll
    for (int ni = 0; ni < 4; ++ni)
      b[ni] = *(const s16x8*)&Bs[(wc * 64 + ni * 16 + lo) * 32 + hi * 8];
#pragma unroll
    for (int mi = 0; mi < 4; ++mi)
#pragma unroll
      for (int ni = 0; ni < 4; ++ni)
        acc[mi][ni] = __builtin_amdgcn_mfma_f32_16x16x32_bf16(a[mi], b[ni], acc[mi][ni], 0, 0, 0);
    __syncthreads();
  }
  if (which < 2) {
    const float osc = which == 0 ? QSCALE : 1.0f;
    unsigned short* On = (which == 0 ? qb : kb) + (size_t)n * SS * DD;
#pragma unroll
    for (int mi = 0; mi < 4; ++mi) {
      const int r0 = s0 + wr * 64 + mi * 16 + hi * 4;
#pragma unroll
      for (int ni = 0; ni < 4; ++ni) {
        const int col = d0 + wc * 64 + ni * 16 + lo;
#pragma unroll
        for (int r = 0; r < 4; ++r)
          On[(size_t)(r0 + r) * DD + col] = f2bf(acc[mi][ni][r] * osc);
      }
    }
  } else {
    unsigned short* On = vtb + (size_t)n * DD * SS;
#pragma unroll
    for (int mi = 0; mi < 4; ++mi) {
      const int r0 = s0 + wr * 64 + mi * 16 + hi * 4;
#pragma unroll
      for (int ni = 0; ni < 4; ++ni) {
        const int col = d0 + wc * 64 + ni * 16 + lo;
        s16x4 v;
#pragma unroll
        for (int r = 0; r < 4; ++r) v[r] = (short)f2bf(acc[mi][ni][r]);
        *(s16x4*)&On[(size_t)col * SS + r0] = v;
      }
    }
  }
}

// ---- flash attention, swapped 32x32 MFMA, in-register softmax (base-2).
// grid 512, n->XCD swizzle: xcd=bid&7, n=xcd+8*(inner>>4) so all 16 blocks
// of one n land on one XCD (K/V working set 1.5MB fits its L2).
// 4 waves x 32 q-rows; lane owns q=lane&31. K/V^T dbuf in LDS (KVBLK=32,
// XOR-swizzled, linear dest + pre-swizzled source). P via per-wave LDS. ----
__global__ __launch_bounds__(256, 2) void k_attn(const unsigned short* __restrict__ qb,
    const unsigned short* __restrict__ kb, const unsigned short* __restrict__ vtb,
    unsigned short* __restrict__ ob) {
  // ushort elems: Ks[2][8192] @0, Vs[2][4096] @16384, P[4][32*40] @24576
  __shared__ __attribute__((aligned(16))) unsigned short lds[29696];  // 58KB
  const int bid = blockIdx.x;
  const int xcd = bid & 7, inner = bid >> 3;
  const int n = xcd + ((inner >> 4) << 3);
  const int sub = inner & 15;
  const int qt = sub & 7, dh = sub >> 3;
  const int tid = threadIdx.x, lane = tid & 63, w = tid >> 6;
  const int l31 = lane & 31, h = lane >> 5;
  const int dblk = dh * 128;
  const unsigned short* Kn = kb + (size_t)n * SS * DD;
  const unsigned short* Vn = vtb + ((size_t)n * DD + dblk) * SS;
  unsigned short* Pw = lds + 24576 + w * 1280;  // [32][40]
  const int qrow = qt * 128 + w * 32 + l31;

  const unsigned short* Qp = qb + ((size_t)n * SS + qrow) * DD + h * 8;
  s16x8 qf[16];
#pragma unroll
  for (int ks = 0; ks < 16; ++ks) qf[ks] = *(const s16x8*)(Qp + ks * 16);

  f32x16 acc[4] = {};
  float mrun = -3.0e38f, lrun = 0.f;

  auto STAGE = [&](int buf, int jt) {
    const int j0 = jt * 32;
    unsigned short* KsB = lds + buf * 8192;
    unsigned short* VsB = lds + 16384 + buf * 4096;
#pragma unroll
    for (int i = 0; i < 4; ++i) {  // K: 32 rows x 256 cols
      const int idx = i * 256 + w * 64 + lane;
      const int row = idx >> 5, c8 = idx & 31;
      GLOAD16(Kn + (size_t)(j0 + row) * DD + ((c8 ^ (row & 7)) << 3),
              KsB + (size_t)(i * 256 + w * 64) * 8);
    }
#pragma unroll
    for (int i = 0; i < 2; ++i) {  // V^T: 128 d-rows x 32 j-cols
      const int idx = i * 256 + w * 64 + lane;
      const int row = idx >> 2, c8 = idx & 3;
      GLOAD16(Vn + (size_t)row * SS + j0 + ((c8 ^ ((row >> 1) & 3)) << 3),
              VsB + (size_t)(i * 256 + w * 64) * 8);
    }
  };

  STAGE(0, 0);
  __syncthreads();

  int cur = 0;
#pragma unroll 1
  for (int jt = 0; jt < 32; ++jt) {
    if (jt + 1 < 32) STAGE(cur ^ 1, jt + 1);
    const unsigned short* Ks = lds + cur * 8192;
    const unsigned short* Vs = lds + 16384 + cur * 4096;
    // ---- QK^T (swapped): lane holds S[j=crow(r,h)][q=l31] ----
    f32x16 sc = {};
    __builtin_amdgcn_s_setprio(1);
#pragma unroll
    for (int ks = 0; ks < 16; ++ks) {
      const s16x8 kf = *(const s16x8*)&Ks[l31 * 256 + ((((ks * 2 + h)) ^ (l31 & 7)) << 3)];
      sc = __builtin_amdgcn_mfma_f32_32x32x16_bf16(kf, qf[ks], sc, 0, 0, 0);
    }
    __builtin_amdgcn_s_setprio(0);
    // ---- online softmax in base-2; row = pair {lane, lane^32} ----
    float pm = sc[0];
#pragma unroll
    for (int i = 1; i < 16; ++i) pm = fmaxf(pm, sc[i]);
    pm = fmaxf(pm, __shfl_xor(pm, 32, 64));
    if (__any(pm > mrun + 8.f)) {
      const float mn = fmaxf(mrun, pm);
      const float corr = exp2f(mrun - mn);
      mrun = mn; lrun *= corr;
#pragma unroll
      for (int dc = 0; dc < 4; ++dc)
#pragma unroll
        for (int i = 0; i < 16; ++i) acc[dc][i] *= corr;
    }
#pragma unroll
    for (int i = 0; i < 16; ++i) sc[i] = exp2f(sc[i] - mrun);
    lrun += (((sc[0] + sc[1]) + (sc[2] + sc[3])) + ((sc[4] + sc[5]) + (sc[6] + sc[7]))) +
            (((sc[8] + sc[9]) + (sc[10] + sc[11])) + ((sc[12] + sc[13]) + (sc[14] + sc[15])));
    // ---- P -> per-wave LDS at [q][crow] (same-wave write->read) ----
#pragma unroll
    for (int t = 0; t < 4; ++t) {
      uint2 u;
      u.x = pk2(sc[t * 4 + 0], sc[t * 4 + 1]);
      u.y = pk2(sc[t * 4 + 2], sc[t * 4 + 3]);
      *(uint2*)&Pw[l31 * 40 + t * 8 + h * 4] = u;
    }
    const s16x8 pa0 = *(const s16x8*)&Pw[l31 * 40 + h * 8];
    const s16x8 pa1 = *(const s16x8*)&Pw[l31 * 40 + 16 + h * 8];
    // ---- PV from Vs[cur] ----
    __builtin_amdgcn_s_setprio(1);
#pragma unroll
    for (int dc = 0; dc < 4; ++dc) {
      const s16x8 vf0 = *(const s16x8*)&Vs[(dc * 32 + l31) * 32 + ((h ^ ((l31 >> 1) & 3)) << 3)];
      acc[dc] = __builtin_amdgcn_mfma_f32_32x32x16_bf16(vf0, pa0, acc[dc], 0, 0, 0);
    }
#pragma unroll
    for (int dc = 0; dc < 4; ++dc) {
      const s16x8 vf1 = *(const s16x8*)&Vs[(dc * 32 + l31) * 32 + (((2 + h) ^ ((l31 >> 1) & 3)) << 3)];
      acc[dc] = __builtin_amdgcn_mfma_f32_32x32x16_bf16(vf1, pa1, acc[dc], 0, 0, 0);
    }
    __builtin_amdgcn_s_setprio(0);
    __syncthreads();  // drains vmcnt(0): next tile staged; waves past cur
    cur ^= 1;
  }
  lrun += __shfl_xor(lrun, 32, 64);
  const float inv = 1.0f / lrun;
  unsigned short* Op = ob + ((size_t)n * SS + qrow) * DD + dblk;
#pragma unroll
  for (int dc = 0; dc < 4; ++dc)
#pragma unroll
    for (int rg = 0; rg < 4; ++rg) {
      uint2 u;
      u.x = pk2(acc[dc][rg * 4 + 0] * inv, acc[dc][rg * 4 + 1] * inv);
      u.y = pk2(acc[dc][rg * 4 + 2] * inv, acc[dc][rg * 4 + 3] * inv);
      *(uint2*)(Op + dc * 32 + rg * 8 + h * 4) = u;
    }
}

// ---- fused proj + bias + residual ----
__global__ __launch_bounds__(256) void k_proj(const unsigned short* __restrict__ ob,
    const unsigned short* __restrict__ wpb, const float* __restrict__ bp,
    const float* __restrict__ x, float* __restrict__ out) {
  __shared__ __attribute__((aligned(16))) unsigned short As[128 * 32];
  __shared__ __attribute__((aligned(16))) unsigned short Bs[128 * 32];
  const int n = blockIdx.z;
  const int s0 = blockIdx.x * 128;
  const int c0 = blockIdx.y * 128;
  const int tid = threadIdx.x;
  const int lane = tid & 63, wid = tid >> 6;
  const int lo = lane & 15, hi = lane >> 4;
  const int wr = wid >> 1, wc = wid & 1;
  const unsigned short* On = ob + (size_t)n * SS * DD;
  f32x4 acc[4][4] = {};
  for (int k0 = 0; k0 < DD; k0 += 32) {
#pragma unroll
    for (int i = 0; i < 2; ++i) {
      const int seg = i * 256 + wid * 64 + lane;
      const int row = seg >> 2, c8 = seg & 3;
      GLOAD16(wpb + (size_t)(c0 + row) * DD + k0 + c8 * 8, As + (size_t)(i * 256 + wid * 64) * 8);
      GLOAD16(On + (size_t)(s0 + row) * DD + k0 + c8 * 8, Bs + (size_t)(i * 256 + wid * 64) * 8);
    }
    __syncthreads();
    s16x8 a[4], b[4];
#pragma unroll
    for (int mi = 0; mi < 4; ++mi)
      a[mi] = *(const s16x8*)&As[(wr * 64 + mi * 16 + lo) * 32 + hi * 8];
#pragma unroll
    for (int ni = 0; ni < 4; ++ni)
      b[ni] = *(const s16x8*)&Bs[(wc * 64 + ni * 16 + lo) * 32 + hi * 8];
#pragma unroll
    for (int mi = 0; mi < 4; ++mi)
#pragma unroll
      for (int ni = 0; ni < 4; ++ni)
        acc[mi][ni] = __builtin_amdgcn_mfma_f32_16x16x32_bf16(a[mi], b[ni], acc[mi][ni], 0, 0, 0);
    __syncthreads();
  }
#pragma unroll
  for (int mi = 0; mi < 4; ++mi) {
#pragma unroll
    for (int r = 0; r < 4; ++r) {
      const int c = c0 + wr * 64 + mi * 16 + hi * 4 + r;
      const float bpc = bp[c];
      const size_t base = ((size_t)n * CD + c) * SS;
#pragma unroll
      for (int ni = 0; ni < 4; ++ni) {
        const int s = s0 + wc * 64 + ni * 16 + lo;
        out[base + s] = acc[mi][ni][r] + bpc + x[base + s];
      }
    }
  }
}

extern "C" void kernel_launch(void* const* d_in, const int* in_sizes, int n_in,
                              void* d_out, int out_size, void* d_ws, size_t ws_size,
                              hipStream_t stream) {
  const float* x  = (const float*)d_in[0];
  const float* t  = (const float*)d_in[1];
  const float* Wt = (const float*)d_in[2];
  const float* bt = (const float*)d_in[3];
  const float* Wq = (const float*)d_in[4];
  const float* Wk = (const float*)d_in[5];
  const float* Wv = (const float*)d_in[6];
  const float* Wp = (const float*)d_in[7];
  const float* bp = (const float*)d_in[8];
  char* ws = (char*)d_ws;
  float* temb        = (float*)ws;                              // 32 KB
  unsigned short* wb = (unsigned short*)(ws + 32768);           // 512 KB (q,k,v,p)
  unsigned short* xb = (unsigned short*)(ws + 557056);          // 16 MB [n,s,c]
  unsigned short* qb = (unsigned short*)(ws + 17334272);        // 16 MB [n,s,d]
  unsigned short* kb = (unsigned short*)(ws + 34111488);        // 16 MB [n,s,d]
  unsigned short* vtb = (unsigned short*)(ws + 50888704);       // 16 MB [n,d,s]
  unsigned short* ob = (unsigned short*)(ws + 67665920);        // 16 MB [n,s,d]
  float* out = (float*)d_out;

  k_misc<<<1056, 256, 0, stream>>>(t, Wt, bt, temb, Wq, Wk, Wv, Wp, wb);
  k_addT<<<dim3(8, 32, 32), 256, 0, stream>>>(x, temb, xb);
  k_qkv<<<dim3(8, 2, 96), 256, 0, stream>>>(xb, wb, qb, kb, vtb);
  k_attn<<<512, 256, 0, stream>>>(qb, kb, vtb, ob);
  k_proj<<<dim3(8, 2, 32), 256, 0, stream>>>(ob, wb + 196608, bp, x, out);
}